// Round 13
// baseline (394.282 us; speedup 1.0000x reference)
//
#include <hip/hip_runtime.h>
#include <math.h>

#define NN 100000
#define NE 1000000
#define F 32
#define FH 16            // features per half-table (3.2 MB: L2-resident per XCD)
#define NBKT 196         // 512-node buckets per direction
#define BKT2 (2 * NBKT)  // 392 buckets (dir0: by dst, dir1: by src)
#define CAPB 5888        // entries per bucket region (mean 5120, +10.7 sigma)
#define EB 4096          // edges per k_bucket block
#define NTILE 6250       // 16-node MFMA tiles

typedef unsigned short ushortT;
typedef unsigned int uintT;
typedef __attribute__((ext_vector_type(8))) short short8;   // 8 bf16 (4 VGPRs)
typedef __attribute__((ext_vector_type(4))) float f32x4;    // MFMA C/D

__device__ inline float bfhi(uintT u)  { return __int_as_float(u & 0xffff0000u); }
__device__ inline float bflo(uintT u)  { return __int_as_float(u << 16); }
__device__ inline uintT f2bf(float f) {                                   // RNE
    uintT u = __float_as_uint(f);
    return (u + 0x7fffu + ((u >> 16) & 1u)) >> 16;
}
// 15-bit positive float (8 exp + 7 mant), RNE
__device__ inline uintT pack15(float f) {
    uintT u = __float_as_uint(f);
    return ((u + 0x7fffu + ((u >> 16) & 1u)) >> 16) & 0x7fffu;
}
__device__ inline float unpack15(uintT v) { return __int_as_float((v & 0x7fffu) << 16); }

// ---------------- pass A: LDS-staged bucket scatter ----------------
__launch_bounds__(256)
__global__ void k_bucket(const int* __restrict__ ei, const float* __restrict__ ew,
                         int* __restrict__ cursor, uint2* __restrict__ stg) {
    __shared__ int se_s[EB];
    __shared__ int se_d[EB];
    __shared__ uintT se_w[EB];
    __shared__ int cntL[BKT2], baseL[BKT2], curL[BKT2];

    const int tid = threadIdx.x;
    const int e0  = blockIdx.x * EB;

    for (int b = tid; b < BKT2; b += 256) { cntL[b] = 0; curL[b] = 0; }
    __syncthreads();

#pragma unroll
    for (int k = 0; k < EB / 256; ++k) {
        int i = tid + k * 256;
        int gid = e0 + i;
        int s = -1, d = -1; uintT w = 0;
        if (gid < NE) {
            s = ei[gid]; d = ei[NE + gid]; w = pack15(ew[gid]);
            atomicAdd(&cntL[d >> 9], 1);
            atomicAdd(&cntL[NBKT + (s >> 9)], 1);
        }
        se_s[i] = s; se_d[i] = d; se_w[i] = w;
    }
    __syncthreads();

    for (int b = tid; b < BKT2; b += 256)
        if (cntL[b] > 0) baseL[b] = atomicAdd(&cursor[b], cntL[b]);
    __syncthreads();

#pragma unroll
    for (int k = 0; k < EB / 256; ++k) {
        int i = tid + k * 256;
        int s = se_s[i];
        if (s < 0) continue;
        int d = se_d[i]; uintT w = se_w[i];
        int b0 = d >> 9;
        int p0 = baseL[b0] + atomicAdd(&curL[b0], 1);
        if (p0 < CAPB) stg[(size_t)b0 * CAPB + p0] = make_uint2(((uintT)s << 15) | w, (uintT)(d & 511));
        int b1 = NBKT + (s >> 9);
        int p1 = baseL[b1] + atomicAdd(&curL[b1], 1);
        if (p1 < CAPB) stg[(size_t)b1 * CAPB + p1] = make_uint2(((uintT)d << 15) | w, (uintT)(s & 511));
    }
}

// ---------------- pass B: per-bucket dense CSR + degrees ----------------
__launch_bounds__(256)
__global__ void k_csr(const int* __restrict__ cursor, const uint2* __restrict__ stg,
                      uintT* __restrict__ entF, int2* __restrict__ meta,
                      float* __restrict__ rdeg) {
    __shared__ int   ncnt[512];
    __shared__ int   nbase[512];
    __shared__ int   ncur[512];
    __shared__ float wsum[512];
    __shared__ int   wavesum[4];

    const int b   = blockIdx.x;
    const int tid = threadIdx.x;
    const int dir = (b >= NBKT) ? 1 : 0;
    const int n0  = (dir ? (b - NBKT) : b) << 9;
    const int c   = min(cursor[b], CAPB);
    const uint2* S = stg + (size_t)b * CAPB;

    for (int l = tid; l < 512; l += 256) { ncnt[l] = 0; ncur[l] = 0; wsum[l] = 0.f; }
    __syncthreads();

    for (int i = tid; i < c; i += 256) {
        uint2 it = S[i];
        atomicAdd(&ncnt[it.y], 1);
        atomicAdd(&wsum[it.y], unpack15(it.x));
    }
    __syncthreads();

    int v0 = ncnt[2 * tid], v1 = ncnt[2 * tid + 1];
    int sp = v0 + v1;
    int lane = tid & 63, wid = tid >> 6;
    int incl = sp;
#pragma unroll
    for (int o = 1; o < 64; o <<= 1) {
        int t = __shfl_up(incl, o, 64);
        if (lane >= o) incl += t;
    }
    if (lane == 63) wavesum[wid] = incl;
    __syncthreads();
    int woff = 0;
    for (int wq = 0; wq < wid; ++wq) woff += wavesum[wq];
    int ex = incl - sp + woff;
    nbase[2 * tid] = ex;
    nbase[2 * tid + 1] = ex + v0;
    __syncthreads();

    const int rb = b * CAPB;
    for (int l = tid; l < 512; l += 256) {
        int node = n0 + l;
        if (node < NN) {
            int seg = dir * NN + node;
            meta[seg] = make_int2(rb + nbase[l], ncnt[l]);
            float s = wsum[l];
            rdeg[seg] = 1.0f / ((s > 0.f) ? s : 1.0f);
        }
    }
    __syncthreads();

    for (int i = tid; i < c; i += 256) {
        uint2 it = S[i];
        int r = atomicAdd(&ncur[it.y], 1);
        entF[rb + nbase[it.y] + r] = it.x;
    }
}

// ---------------- bake normalization into entries ----------------
__launch_bounds__(256)
__global__ void k_norm(const int* __restrict__ cursor, const float* __restrict__ rdeg,
                       uintT* __restrict__ entF) {
    const int b    = blockIdx.x >> 1;
    const int half = blockIdx.x & 1;
    const int c    = min(cursor[b], CAPB);
    const int opp  = (b < NBKT) ? NN : 0;
    uintT* E = entF + (size_t)b * CAPB;
    for (int i = half * 256 + threadIdx.x; i < c; i += 512) {
        uintT e = E[i];
        int nbr = e >> 15;
        float nm = unpack15(e) * rdeg[opp + nbr];
        E[i] = ((uintT)nbr << 15) | pack15(nm);
    }
}

// ---------------- combined weights -> MFMA B-fragment layout (bf16) ----------------
// kc 0: W00+W10-W02-W12 | 1: W01 | 2: W11 | 3: 2*W02 | 4: 2*W12   (T2=2*P2-x folded; H0==0)
__global__ void k_wprep(const float* __restrict__ Wz, const float* __restrict__ Wh,
                        ushortT* __restrict__ wfrag) {
    int gid = blockIdx.x * 256 + threadIdx.x;
    if (gid >= 20 * 512) return;
    int f = gid >> 9, rem = gid & 511;
    int l = rem >> 3, r = rem & 7;
    int kc = f >> 2, nt = f & 3;
    int n = nt * 16 + (l & 15);
    int fi = (l >> 4) * 8 + r;
    int jc = n & 31;
    const float* W = (n >= 32) ? Wh : Wz;
#define WDK(d, k) W[((((d) * 3 + (k)) * 64) + fi) * 32 + jc]
    float v;
    if      (kc == 0) v = WDK(0,0) + WDK(1,0) - WDK(0,2) - WDK(1,2);
    else if (kc == 1) v = WDK(0,1);
    else if (kc == 2) v = WDK(1,1);
    else if (kc == 3) v = 2.0f * WDK(0,2);
    else              v = 2.0f * WDK(1,2);
#undef WDK
    wfrag[gid] = (ushortT)f2bf(v);
}

// ---------------- x -> raw bf16 HALF-tables (xbA: feats 0-15, xbB: 16-31) ----------
__global__ void k_conv(const float* __restrict__ x,
                       ushortT* __restrict__ xbA, ushortT* __restrict__ xbB) {
    int i = blockIdx.x * 256 + threadIdx.x;          // 8 threads per node row
    if (i >= NN * 8) return;
    int node = i >> 3, q = i & 7;
    float4 a = *(const float4*)(x + (long)node * F + q * 4);
    ushortT* dst = ((q >> 2) ? xbB : xbA) + (long)node * FH + (q & 3) * 4;
    uint2 o;
    o.x = f2bf(a.x) | (f2bf(a.y) << 16);
    o.y = f2bf(a.z) | (f2bf(a.w) << 16);
    *(uint2*)dst = o;
}

// ---------------- hop pass: wave per (node[,dir]), HALF feature table ----------------
// lane = g*8 + q : g = edge slot (0..7), q = feature pair (0..7; 2 bf16 = 4 B)
// Table is one 3.2 MB half -> L2-resident per XCD. Entries batch-loaded 64 at a
// time (coalesced) and broadcast via __shfl; pad entries are 0 -> nm = 0.
__launch_bounds__(256)
__global__ void k_hop(const int2* __restrict__ meta, const uintT* __restrict__ entF,
                      const ushortT* __restrict__ tbl0, const ushortT* __restrict__ tbl1,
                      ushortT* __restrict__ out0, ushortT* __restrict__ out1,
                      int ndirs, int dirbase) {
    int wid = blockIdx.x * 4 + (threadIdx.x >> 6);
    int n, dir;
    if (ndirs == 2) {
        if (wid >= 2 * NN) return;
        n = wid >> 1; dir = wid & 1;
    } else {
        if (wid >= NN) return;
        n = wid; dir = dirbase;
    }
    int2 m = meta[dir * NN + n];
    int base = m.x, c = m.y;
    int lane = threadIdx.x & 63;
    int g = lane >> 3, q = lane & 7;
    const ushortT* tbl = dir ? tbl1 : tbl0;
    float ax = 0.f, ay = 0.f;
    for (int j0 = 0; j0 < c; j0 += 64) {
        int nb = min(c - j0, 64);
        uintT ent = (lane < nb) ? entF[base + j0 + lane] : 0u;   // coalesced batch
        for (int it = g; it - g < nb; it += 8) {                 // 8 items per wave-iter
            uintT e = __shfl(ent, it, 64);                       // pad -> nm = 0
            int idx = e >> 15;
            float nm = unpack15(e);
            uintT v = *(const uintT*)(tbl + (long)idx * FH + q * 2);
            ax += nm * bflo(v);
            ay += nm * bfhi(v);
        }
    }
    ax += __shfl_xor(ax, 8, 64);  ay += __shfl_xor(ay, 8, 64);
    ax += __shfl_xor(ax, 16, 64); ay += __shfl_xor(ay, 16, 64);
    ax += __shfl_xor(ax, 32, 64); ay += __shfl_xor(ay, 32, 64);
    if (g == 0) {
        uintT o = f2bf(ax) | (f2bf(ay) << 16);
        *(uintT*)((dir ? out1 : out0) + (long)n * FH + q * 2) = o;
    }
}

// ---------------- MFMA GEMM [100K x 160]@[160 x 64] + gates + GRU + head ----------------
// A-layout: lane holds A[m=lane&15][k=quad*8+j]; features come from half-tables:
// half = quad>>1, sub = (quad&1)*8 -> addr = node*FH + sub
// C/D: D[row=quad*4+r][col=lane&15]
__launch_bounds__(256)
__global__ void k_final(const ushortT* __restrict__ xbA, const ushortT* __restrict__ xbB,
                        const ushortT* __restrict__ t1oA, const ushortT* __restrict__ t1oB,
                        const ushortT* __restrict__ t1iA, const ushortT* __restrict__ t1iB,
                        const ushortT* __restrict__ p2oA, const ushortT* __restrict__ p2oB,
                        const ushortT* __restrict__ p2iA, const ushortT* __restrict__ p2iB,
                        const ushortT* __restrict__ wfrag,
                        const float* __restrict__ bz, const float* __restrict__ bh,
                        const float* __restrict__ Wl, const float* __restrict__ bl,
                        float* __restrict__ y, int nwaves) {
    const int lane = threadIdx.x & 63;
    const int wgid = blockIdx.x * 4 + (threadIdx.x >> 6);
    const int quad = lane >> 4;
    const int c0   = lane & 15;

    union U8 { uint4 u; short8 s; };

    short8 bfr[20];
#pragma unroll
    for (int f = 0; f < 20; ++f) {
        U8 t; t.u = *(const uint4*)(wfrag + f * 512 + lane * 8);
        bfr[f] = t.s;
    }

    const float bz0 = bz[c0], bz1 = bz[c0 + 16];
    const float bh0 = bh[c0], bh1 = bh[c0 + 16];
    const float wl0 = Wl[c0], wl1 = Wl[c0 + 16];
    const float blv = bl[0];

    const ushortT* srcs[5][2] = {{xbA, xbB}, {t1oA, t1oB}, {t1iA, t1iB},
                                 {p2oA, p2oB}, {p2iA, p2iB}};
    const int halfsel = quad >> 1;
    const int sub     = (quad & 1) * 8;

    for (int t = wgid; t < NTILE; t += nwaves) {
        const long off = (long)(t * 16 + c0) * FH + sub;
        f32x4 a0 = {0.f, 0.f, 0.f, 0.f}, a1 = a0, a2 = a0, a3 = a0;
#pragma unroll
        for (int kc = 0; kc < 5; ++kc) {
            U8 av; av.u = *(const uint4*)(srcs[kc][halfsel] + off);
            a0 = __builtin_amdgcn_mfma_f32_16x16x32_bf16(av.s, bfr[kc * 4 + 0], a0, 0, 0, 0);
            a1 = __builtin_amdgcn_mfma_f32_16x16x32_bf16(av.s, bfr[kc * 4 + 1], a1, 0, 0, 0);
            a2 = __builtin_amdgcn_mfma_f32_16x16x32_bf16(av.s, bfr[kc * 4 + 2], a2, 0, 0, 0);
            a3 = __builtin_amdgcn_mfma_f32_16x16x32_bf16(av.s, bfr[kc * 4 + 3], a3, 0, 0, 0);
        }
        float res[4];
#pragma unroll
        for (int r = 0; r < 4; ++r) {
            float gz = a0[r] + bz0, gh = a2[r] + bh0;
            float z  = 1.0f / (1.0f + __expf(-gz));
            float e2 = __expf(2.0f * gh);
            float ht = 1.0f - 2.0f / (e2 + 1.0f);
            float v  = fmaxf((1.0f - z) * ht, 0.0f) * wl0;
            gz = a1[r] + bz1; gh = a3[r] + bh1;
            z  = 1.0f / (1.0f + __expf(-gz));
            e2 = __expf(2.0f * gh);
            ht = 1.0f - 2.0f / (e2 + 1.0f);
            v += fmaxf((1.0f - z) * ht, 0.0f) * wl1;
            res[r] = v;
        }
#pragma unroll
        for (int o = 1; o < 16; o <<= 1) {
            res[0] += __shfl_xor(res[0], o, 64);
            res[1] += __shfl_xor(res[1], o, 64);
            res[2] += __shfl_xor(res[2], o, 64);
            res[3] += __shfl_xor(res[3], o, 64);
        }
        if (c0 == 0) {
            f32x4 out = {res[0] + blv, res[1] + blv, res[2] + blv, res[3] + blv};
            *(f32x4*)(y + t * 16 + quad * 4) = out;
        }
    }
}

extern "C" void kernel_launch(void* const* d_in, const int* in_sizes, int n_in,
                              void* d_out, int out_size, void* d_ws, size_t ws_size,
                              hipStream_t stream) {
    const float* x  = (const float*)d_in[0];
    const int*   ei = (const int*)  d_in[1];
    const float* ew = (const float*)d_in[2];
    // d_in[3]=h, d_in[4]=c unused (H0 forced to 0); d_in[7]=Wr, d_in[8]=br dead (R*H0==0)
    const float* Wz = (const float*)d_in[5];
    const float* bz = (const float*)d_in[6];
    const float* Wh = (const float*)d_in[9];
    const float* bh = (const float*)d_in[10];
    const float* Wl = (const float*)d_in[11];
    const float* bl = (const float*)d_in[12];
    float* y = (float*)d_out;

    // ---- workspace (~43 MB): stg aliased over the t1/p2 half-table region ----
    const size_t segs = 2 * NN;
    const long   NH   = (long)NN * FH;                       // ushorts per half-table
    int*     cursor = (int*)d_ws;                            // 400
    int2*    meta   = (int2*)(cursor + 400);                 // 2NN
    float*   rdeg   = (float*)(meta + segs);                 // 2NN
    uintT*   entF   = (uintT*)(rdeg + segs);                 // 392*CAPB (9.2 MB)
    ushortT* wfrag  = (ushortT*)(entF + (size_t)BKT2 * CAPB);// 10240
    ushortT* xbA    = wfrag + 10240;                         // NOT aliased (written first)
    ushortT* xbB    = xbA + NH;
    ushortT* t1oA   = xbB + NH;                              // 8 half-tables (25.6 MB)
    ushortT* t1iA   = t1oA + NH;
    ushortT* t1oB   = t1iA + NH;
    ushortT* t1iB   = t1oB + NH;
    ushortT* p2oA   = t1iB + NH;
    ushortT* p2iA   = p2oA + NH;
    ushortT* p2oB   = p2iA + NH;
    ushortT* p2iB   = p2oB + NH;
    uint2*   stg    = (uint2*)t1oA;                          // 18.5 MB <= 25.6 MB, dead after k_csr

    hipMemsetAsync(cursor, 0, BKT2 * sizeof(int), stream);

    const int B = 256;
    k_conv<<<(NN * 8 + B - 1) / B, B, 0, stream>>>(x, xbA, xbB);
    k_wprep<<<40, B, 0, stream>>>(Wz, Wh, wfrag);
    k_bucket<<<(NE + EB - 1) / EB, B, 0, stream>>>(ei, ew, cursor, stg);
    k_csr<<<BKT2, B, 0, stream>>>(cursor, stg, entF, meta, rdeg);
    k_norm<<<2 * BKT2, B, 0, stream>>>(cursor, rdeg, entF);

    const int gb2 = (2 * NN + 3) / 4;   // dual-dir passes
    const int gb1 = (NN + 3) / 4;       // single-dir passes
    // hop1: both dirs gather the same x-half (3.2 MB, L2-resident)
    k_hop<<<gb2, B, 0, stream>>>(meta, entF, xbA, xbA, t1oA, t1iA, 2, 0);
    k_hop<<<gb2, B, 0, stream>>>(meta, entF, xbB, xbB, t1oB, t1iB, 2, 0);
    // hop2: one dir x one half per pass (table 3.2 MB each)
    k_hop<<<gb1, B, 0, stream>>>(meta, entF, t1oA, t1oA, p2oA, p2oA, 1, 0);
    k_hop<<<gb1, B, 0, stream>>>(meta, entF, t1iA, t1iA, p2iA, p2iA, 1, 1);
    k_hop<<<gb1, B, 0, stream>>>(meta, entF, t1oB, t1oB, p2oB, p2oB, 1, 0);
    k_hop<<<gb1, B, 0, stream>>>(meta, entF, t1iB, t1iB, p2iB, p2iB, 1, 1);

    const int fblocks = 512;
    k_final<<<fblocks, B, 0, stream>>>(xbA, xbB, t1oA, t1oB, t1iA, t1iB,
                                       p2oA, p2oB, p2iA, p2iB, wfrag,
                                       bz, bh, Wl, bl, y, fblocks * 4);
}

// Round 14
// 280.004 us; speedup vs baseline: 1.4081x; 1.4081x over previous
//
#include <hip/hip_runtime.h>
#include <math.h>

#define NN 100000
#define NE 1000000
#define F 32
#define NBKT 196         // 512-node buckets per direction
#define BKT2 (2 * NBKT)  // 392 buckets (dir0: by dst, dir1: by src)
#define CAPB 5888        // entries per bucket region (mean 5120, +10.7 sigma)
#define EB 4096          // edges per k_bucket block
#define NTILE 6250       // 16-node MFMA tiles

typedef unsigned short ushortT;
typedef unsigned int uintT;
typedef __attribute__((ext_vector_type(8))) short short8;   // 8 bf16 (4 VGPRs)
typedef __attribute__((ext_vector_type(4))) float f32x4;    // MFMA C/D

__device__ inline float bfhi(uintT u)  { return __int_as_float(u & 0xffff0000u); }
__device__ inline float bflo(uintT u)  { return __int_as_float(u << 16); }
__device__ inline uintT f2bf(float f) {                                   // RNE
    uintT u = __float_as_uint(f);
    return (u + 0x7fffu + ((u >> 16) & 1u)) >> 16;
}
// 15-bit positive float (8 exp + 7 mant), RNE
__device__ inline uintT pack15(float f) {
    uintT u = __float_as_uint(f);
    return ((u + 0x7fffu + ((u >> 16) & 1u)) >> 16) & 0x7fffu;
}
__device__ inline float unpack15(uintT v) { return __int_as_float((v & 0x7fffu) << 16); }

// ---------------- pass A: LDS-staged bucket scatter ----------------
__launch_bounds__(256)
__global__ void k_bucket(const int* __restrict__ ei, const float* __restrict__ ew,
                         int* __restrict__ cursor, uint2* __restrict__ stg) {
    __shared__ int se_s[EB];
    __shared__ int se_d[EB];
    __shared__ uintT se_w[EB];
    __shared__ int cntL[BKT2], baseL[BKT2], curL[BKT2];

    const int tid = threadIdx.x;
    const int e0  = blockIdx.x * EB;

    for (int b = tid; b < BKT2; b += 256) { cntL[b] = 0; curL[b] = 0; }
    __syncthreads();

#pragma unroll
    for (int k = 0; k < EB / 256; ++k) {
        int i = tid + k * 256;
        int gid = e0 + i;
        int s = -1, d = -1; uintT w = 0;
        if (gid < NE) {
            s = ei[gid]; d = ei[NE + gid]; w = pack15(ew[gid]);
            atomicAdd(&cntL[d >> 9], 1);
            atomicAdd(&cntL[NBKT + (s >> 9)], 1);
        }
        se_s[i] = s; se_d[i] = d; se_w[i] = w;
    }
    __syncthreads();

    for (int b = tid; b < BKT2; b += 256)
        if (cntL[b] > 0) baseL[b] = atomicAdd(&cursor[b], cntL[b]);
    __syncthreads();

#pragma unroll
    for (int k = 0; k < EB / 256; ++k) {
        int i = tid + k * 256;
        int s = se_s[i];
        if (s < 0) continue;
        int d = se_d[i]; uintT w = se_w[i];
        int b0 = d >> 9;
        int p0 = baseL[b0] + atomicAdd(&curL[b0], 1);
        if (p0 < CAPB) stg[(size_t)b0 * CAPB + p0] = make_uint2(((uintT)s << 15) | w, (uintT)(d & 511));
        int b1 = NBKT + (s >> 9);
        int p1 = baseL[b1] + atomicAdd(&curL[b1], 1);
        if (p1 < CAPB) stg[(size_t)b1 * CAPB + p1] = make_uint2(((uintT)d << 15) | w, (uintT)(s & 511));
    }
}

// ---------------- pass B: per-bucket dense CSR + degrees ----------------
__launch_bounds__(256)
__global__ void k_csr(const int* __restrict__ cursor, const uint2* __restrict__ stg,
                      uintT* __restrict__ entF, int2* __restrict__ meta,
                      float* __restrict__ rdeg) {
    __shared__ int   ncnt[512];
    __shared__ int   nbase[512];
    __shared__ int   ncur[512];
    __shared__ float wsum[512];
    __shared__ int   wavesum[4];

    const int b   = blockIdx.x;
    const int tid = threadIdx.x;
    const int dir = (b >= NBKT) ? 1 : 0;
    const int n0  = (dir ? (b - NBKT) : b) << 9;
    const int c   = min(cursor[b], CAPB);
    const uint2* S = stg + (size_t)b * CAPB;

    for (int l = tid; l < 512; l += 256) { ncnt[l] = 0; ncur[l] = 0; wsum[l] = 0.f; }
    __syncthreads();

    for (int i = tid; i < c; i += 256) {
        uint2 it = S[i];
        atomicAdd(&ncnt[it.y], 1);
        atomicAdd(&wsum[it.y], unpack15(it.x));
    }
    __syncthreads();

    int v0 = ncnt[2 * tid], v1 = ncnt[2 * tid + 1];
    int sp = v0 + v1;
    int lane = tid & 63, wid = tid >> 6;
    int incl = sp;
#pragma unroll
    for (int o = 1; o < 64; o <<= 1) {
        int t = __shfl_up(incl, o, 64);
        if (lane >= o) incl += t;
    }
    if (lane == 63) wavesum[wid] = incl;
    __syncthreads();
    int woff = 0;
    for (int wq = 0; wq < wid; ++wq) woff += wavesum[wq];
    int ex = incl - sp + woff;
    nbase[2 * tid] = ex;
    nbase[2 * tid + 1] = ex + v0;
    __syncthreads();

    const int rb = b * CAPB;
    for (int l = tid; l < 512; l += 256) {
        int node = n0 + l;
        if (node < NN) {
            int seg = dir * NN + node;
            meta[seg] = make_int2(rb + nbase[l], ncnt[l]);
            float s = wsum[l];
            rdeg[seg] = 1.0f / ((s > 0.f) ? s : 1.0f);
        }
    }
    __syncthreads();

    for (int i = tid; i < c; i += 256) {
        uint2 it = S[i];
        int r = atomicAdd(&ncur[it.y], 1);
        entF[rb + nbase[it.y] + r] = it.x;
    }
}

// ---------------- combined weights -> MFMA B-fragment layout (bf16) ----------------
// kc 0: W00+W10-W02-W12 | 1: W01 | 2: W11 | 3: 2*W02 | 4: 2*W12   (T2=2*P2-x folded; H0==0)
__global__ void k_wprep(const float* __restrict__ Wz, const float* __restrict__ Wh,
                        ushortT* __restrict__ wfrag) {
    int gid = blockIdx.x * 256 + threadIdx.x;
    if (gid >= 20 * 512) return;
    int f = gid >> 9, rem = gid & 511;
    int l = rem >> 3, r = rem & 7;
    int kc = f >> 2, nt = f & 3;
    int n = nt * 16 + (l & 15);
    int fi = (l >> 4) * 8 + r;
    int jc = n & 31;
    const float* W = (n >= 32) ? Wh : Wz;
#define WDK(d, k) W[((((d) * 3 + (k)) * 64) + fi) * 32 + jc]
    float v;
    if      (kc == 0) v = WDK(0,0) + WDK(1,0) - WDK(0,2) - WDK(1,2);
    else if (kc == 1) v = WDK(0,1);
    else if (kc == 2) v = WDK(1,1);
    else if (kc == 3) v = 2.0f * WDK(0,2);
    else              v = 2.0f * WDK(1,2);
#undef WDK
    wfrag[gid] = (ushortT)f2bf(v);
}

// ---------------- x -> raw bf16 rows ----------------
__global__ void k_conv(const float* __restrict__ x, ushortT* __restrict__ xbr) {
    int i = blockIdx.x * 256 + threadIdx.x;
    if (i >= NN * F / 8) return;
    const float4* p = (const float4*)x + (long)i * 2;
    float4 a = p[0], b = p[1];
    uint4 o;
    o.x = f2bf(a.x) | (f2bf(a.y) << 16);
    o.y = f2bf(a.z) | (f2bf(a.w) << 16);
    o.z = f2bf(b.x) | (f2bf(b.y) << 16);
    o.w = f2bf(b.z) | (f2bf(b.w) << 16);
    ((uint4*)xbr)[i] = o;
}

// ---------------- hop: wave per (node, direction) ----------------
// lane = g*8 + q : g = edge slot (0..7), q = feature quad (4 bf16 = 8 B)
// Norm applied in-flight: nm = w15 * rdeg[opp + nbr] (rdeg table is 800 KB, L2-hot;
// measured free vs baked norms in R9/R12 A/B).
// swizzle=0 (hop1): wid = blk*4+w, n = wid>>1, dir = wid&1   (shared x table)
// swizzle=1 (hop2): dir = blk&1, n = (blk>>1)*4 + w          (dir-parity XCD split:
//   with round-robin blockIdx->XCD, even XCDs gather only t1o, odd only t1i)
__launch_bounds__(256)
__global__ void k_hop(const int2* __restrict__ meta, const uintT* __restrict__ entF,
                      const float* __restrict__ rdeg,
                      const ushortT* __restrict__ fo, const ushortT* __restrict__ fi,
                      ushortT* __restrict__ oo, ushortT* __restrict__ oi, int swizzle) {
    const int w = threadIdx.x >> 6;
    int n, dir;
    if (swizzle) { dir = blockIdx.x & 1; n = (blockIdx.x >> 1) * 4 + w; }
    else         { int wid = blockIdx.x * 4 + w; n = wid >> 1; dir = wid & 1; }
    if (n >= NN) return;
    int2 m = meta[dir * NN + n];
    int base = m.x, c = m.y;
    int lane = threadIdx.x & 63;
    int g = lane >> 3, q = lane & 7;
    const int opp = dir ? 0 : NN;
    const ushortT* feat = dir ? fi : fo;
    float4 acc = make_float4(0.f, 0.f, 0.f, 0.f);
    for (int j = base + g; j < base + c; j += 8) {
        uintT e = entF[j];                       // 8 lanes same addr -> broadcast
        int idx = e >> 15;
        float nm = unpack15(e) * rdeg[opp + idx];
        uint2 v = *(const uint2*)(feat + (long)idx * F + q * 4);
        acc.x += nm * bflo(v.x);
        acc.y += nm * bfhi(v.x);
        acc.z += nm * bflo(v.y);
        acc.w += nm * bfhi(v.y);
    }
#pragma unroll
    for (int mm = 8; mm < 64; mm <<= 1) {
        acc.x += __shfl_xor(acc.x, mm, 64);
        acc.y += __shfl_xor(acc.y, mm, 64);
        acc.z += __shfl_xor(acc.z, mm, 64);
        acc.w += __shfl_xor(acc.w, mm, 64);
    }
    if (g == 0) {
        uint2 o = make_uint2(f2bf(acc.x) | (f2bf(acc.y) << 16),
                             f2bf(acc.z) | (f2bf(acc.w) << 16));
        *(uint2*)((dir ? oi : oo) + (long)n * F + q * 4) = o;
    }
}

// ---------------- MFMA GEMM [100K x 160]@[160 x 64] + gates + GRU + head ----------------
// A-layout: lane holds A[m=lane&15][k=quad*8+j] -> addr = tile + (lane&15)*F + quad*8
// C/D: D[row=quad*4+r][col=lane&15]
__launch_bounds__(256)
__global__ void k_final(const ushortT* __restrict__ xb,
                        const ushortT* __restrict__ t1o, const ushortT* __restrict__ t1i,
                        const ushortT* __restrict__ p2o, const ushortT* __restrict__ p2i,
                        const ushortT* __restrict__ wfrag,
                        const float* __restrict__ bz, const float* __restrict__ bh,
                        const float* __restrict__ Wl, const float* __restrict__ bl,
                        float* __restrict__ y, int nwaves) {
    const int lane = threadIdx.x & 63;
    const int wgid = blockIdx.x * 4 + (threadIdx.x >> 6);
    const int quad = lane >> 4;
    const int c0   = lane & 15;

    union U8 { uint4 u; short8 s; };

    short8 bfr[20];
#pragma unroll
    for (int f = 0; f < 20; ++f) {
        U8 t; t.u = *(const uint4*)(wfrag + f * 512 + lane * 8);
        bfr[f] = t.s;
    }

    const float bz0 = bz[c0], bz1 = bz[c0 + 16];
    const float bh0 = bh[c0], bh1 = bh[c0 + 16];
    const float wl0 = Wl[c0], wl1 = Wl[c0 + 16];
    const float blv = bl[0];

    const ushortT* srcs[5] = {xb, t1o, t1i, p2o, p2i};

    for (int t = wgid; t < NTILE; t += nwaves) {
        const long off = (long)t * 16 * F + (long)c0 * F + quad * 8;
        f32x4 a0 = {0.f, 0.f, 0.f, 0.f}, a1 = a0, a2 = a0, a3 = a0;
#pragma unroll
        for (int kc = 0; kc < 5; ++kc) {
            U8 av; av.u = *(const uint4*)(srcs[kc] + off);
            a0 = __builtin_amdgcn_mfma_f32_16x16x32_bf16(av.s, bfr[kc * 4 + 0], a0, 0, 0, 0);
            a1 = __builtin_amdgcn_mfma_f32_16x16x32_bf16(av.s, bfr[kc * 4 + 1], a1, 0, 0, 0);
            a2 = __builtin_amdgcn_mfma_f32_16x16x32_bf16(av.s, bfr[kc * 4 + 2], a2, 0, 0, 0);
            a3 = __builtin_amdgcn_mfma_f32_16x16x32_bf16(av.s, bfr[kc * 4 + 3], a3, 0, 0, 0);
        }
        float res[4];
#pragma unroll
        for (int r = 0; r < 4; ++r) {
            float gz = a0[r] + bz0, gh = a2[r] + bh0;
            float z  = 1.0f / (1.0f + __expf(-gz));
            float e2 = __expf(2.0f * gh);
            float ht = 1.0f - 2.0f / (e2 + 1.0f);
            float v  = fmaxf((1.0f - z) * ht, 0.0f) * wl0;
            gz = a1[r] + bz1; gh = a3[r] + bh1;
            z  = 1.0f / (1.0f + __expf(-gz));
            e2 = __expf(2.0f * gh);
            ht = 1.0f - 2.0f / (e2 + 1.0f);
            v += fmaxf((1.0f - z) * ht, 0.0f) * wl1;
            res[r] = v;
        }
#pragma unroll
        for (int o = 1; o < 16; o <<= 1) {
            res[0] += __shfl_xor(res[0], o, 64);
            res[1] += __shfl_xor(res[1], o, 64);
            res[2] += __shfl_xor(res[2], o, 64);
            res[3] += __shfl_xor(res[3], o, 64);
        }
        if (c0 == 0) {
            f32x4 out = {res[0] + blv, res[1] + blv, res[2] + blv, res[3] + blv};
            *(f32x4*)(y + t * 16 + quad * 4) = out;
        }
    }
}

extern "C" void kernel_launch(void* const* d_in, const int* in_sizes, int n_in,
                              void* d_out, int out_size, void* d_ws, size_t ws_size,
                              hipStream_t stream) {
    const float* x  = (const float*)d_in[0];
    const int*   ei = (const int*)  d_in[1];
    const float* ew = (const float*)d_in[2];
    // d_in[3]=h, d_in[4]=c unused (H0 forced to 0); d_in[7]=Wr, d_in[8]=br dead (R*H0==0)
    const float* Wz = (const float*)d_in[5];
    const float* bz = (const float*)d_in[6];
    const float* Wh = (const float*)d_in[9];
    const float* bh = (const float*)d_in[10];
    const float* Wl = (const float*)d_in[11];
    const float* bl = (const float*)d_in[12];
    float* y = (float*)d_out;

    // ---- workspace (~44 MB): stg aliased over t1o.. (dead after k_csr) ----
    const size_t segs = 2 * NN;
    const long   NFW  = (long)NN * F;                        // ushorts per feature buf
    int*     cursor = (int*)d_ws;                            // 400
    int2*    meta   = (int2*)(cursor + 400);                 // 2NN
    float*   rdeg   = (float*)(meta + segs);                 // 2NN
    uintT*   entF   = (uintT*)(rdeg + segs);                 // 392*CAPB (9.2 MB)
    ushortT* wfrag  = (ushortT*)(entF + (size_t)BKT2 * CAPB);// 10240
    ushortT* xbr    = wfrag + 10240;                         // written early, NOT aliased
    ushortT* t1o    = xbr + NFW;
    ushortT* t1i    = t1o + NFW;
    ushortT* p2o    = t1i + NFW;
    ushortT* p2i    = p2o + NFW;
    uint2*   stg    = (uint2*)t1o;                           // 18.5 MB <= 25.6 MB (t1o..p2i)

    hipMemsetAsync(cursor, 0, BKT2 * sizeof(int), stream);

    const int B = 256;
    k_conv<<<(NN * F / 8 + B - 1) / B, B, 0, stream>>>(x, xbr);
    k_wprep<<<40, B, 0, stream>>>(Wz, Wh, wfrag);
    k_bucket<<<(NE + EB - 1) / EB, B, 0, stream>>>(ei, ew, cursor, stg);
    k_csr<<<BKT2, B, 0, stream>>>(cursor, stg, entF, meta, rdeg);
    // hop1: gather raw x -> raw t1{o,i}; interleaved dirs (shared 6.4 MB x table)
    k_hop<<<(2 * NN + 3) / 4, B, 0, stream>>>(meta, entF, rdeg, xbr, xbr, t1o, t1i, 0);
    // hop2: gather raw t1 -> raw p2{o,i}; dir-parity blocks for per-XCD table split
    k_hop<<<2 * ((NN + 3) / 4), B, 0, stream>>>(meta, entF, rdeg, t1o, t1i, p2o, p2i, 1);
    const int fblocks = 512;
    k_final<<<fblocks, B, 0, stream>>>(xbr, t1o, t1i, p2o, p2i, wfrag,
                                       bz, bh, Wl, bl, y, fblocks * 4);
}